// Round 13
// baseline (282.272 us; speedup 1.0000x reference)
//
#include <hip/hip_runtime.h>
#include <hip/hip_bf16.h>

#define NB 4
#define NS 2048
#define ND 1024
#define NH 16
#define NHD 64
#define NM (NB*NS)   // 8192 rows of X

typedef __bf16 bf16_t;
typedef bf16_t bf8  __attribute__((ext_vector_type(8)));
typedef bf16_t bf4v __attribute__((ext_vector_type(4)));
typedef float  f4   __attribute__((ext_vector_type(4)));

// async global -> LDS, 16B per lane (dest = wave-uniform base + lane*16)
#define GLDS16(g, l) __builtin_amdgcn_global_load_lds( \
    (const __attribute__((address_space(1))) void*)(g), \
    (__attribute__((address_space(3))) void*)(l), 16, 0, 0)

// ---------------- fused fp32 -> bf16 conversion (X + 4 weights, one launch) ----
__global__ __launch_bounds__(256) void cvt_all(const float* __restrict__ x,
                                               const float* __restrict__ wq,
                                               const float* __restrict__ wk,
                                               const float* __restrict__ wv,
                                               const float* __restrict__ wo,
                                               bf16_t* __restrict__ Xb,
                                               bf16_t* __restrict__ Wqkv,
                                               bf16_t* __restrict__ Wob) {
    const int i = blockIdx.x * 256 + threadIdx.x;   // float4 index, total 3145728
    const float* src;
    bf16_t* dst;
    int off;
    if (i < 2097152) {            // X: 8192*1024 floats = 2097152 float4
        src = x; dst = Xb; off = i;
    } else {
        const int j = i - 2097152;        // [0, 4*262144)
        const int w = j >> 18;            // which weight
        off = j & 262143;
        src = (w == 0 ? wq : w == 1 ? wk : w == 2 ? wv : wo);
        dst = (w == 3 ? Wob : Wqkv + ((size_t)w << 20));
    }
    const float4 v = ((const float4*)src)[off];
    bf4v o;
    o[0] = (bf16_t)v.x; o[1] = (bf16_t)v.y; o[2] = (bf16_t)v.z; o[3] = (bf16_t)v.w;
    ((bf4v*)dst)[off] = o;
}

// ---------------- fused QKV GEMM ----------------
// v12: depth-1 2-phase pipeline (T3-minimum): BK=32 double-buffered LDS; the
// next step's 4 global_load_lds are ISSUED BEFORE the current step's compute,
// so staging latency overlaps the 16 MFMAs + ds_reads; ONE __syncthreads per
// step (drains the in-flight loads only after compute has run). 32 KB LDS.
// Epilogue/XCD swizzle = v11 (V stored transposed [b,h,d,s]).
__global__ __launch_bounds__(256) void gemm_qkv(const bf16_t* __restrict__ A,
                                                const bf16_t* __restrict__ Bw,
                                                const float* __restrict__ bq,
                                                const float* __restrict__ bk,
                                                const float* __restrict__ bv,
                                                bf16_t* __restrict__ Qh,
                                                bf16_t* __restrict__ Kh,
                                                bf16_t* __restrict__ VTh) {
    __shared__ __align__(16) bf16_t As[2][128 * 32];
    __shared__ __align__(16) bf16_t Bs[2][128 * 32];
    const int t = threadIdx.x;
    const int wave = t >> 6, lane = t & 63, ln = lane & 15, quad = lane >> 4;
    const int wm = (wave >> 1) * 64, wn = (wave & 1) * 64;
    // chunked XCD remap: XCD x gets flat ids [x*192, (x+1)*192)
    int flat = blockIdx.y * gridDim.x + blockIdx.x;
    flat = (flat & 7) * 192 + (flat >> 3);
    const int m0 = (flat / gridDim.x) * 128, n0 = (flat % gridDim.x) * 128;
    const int K = 1024;

    f4 acc[4][4];
    const f4 z = {0.f, 0.f, 0.f, 0.f};
#pragma unroll
    for (int i = 0; i < 4; ++i)
#pragma unroll
        for (int j = 0; j < 4; ++j) acc[i][j] = z;

    const int srow = wave * 16 + (lane >> 2);
    const int scol = (lane & 3) * 8;
    const bf16_t* Ag0 = A  + (size_t)(m0 + srow) * K + scol;
    const bf16_t* Ag1 = A  + (size_t)(m0 + srow + 64) * K + scol;
    const bf16_t* Bg0 = Bw + (size_t)(n0 + srow) * K + scol;
    const bf16_t* Bg1 = Bw + (size_t)(n0 + srow + 64) * K + scol;
    const int so0 = srow * 32 + scol, so1 = (srow + 64) * 32 + scol;

    // prologue: stage k=0 into buf 0
    GLDS16(Ag0, &As[0][so0]);
    GLDS16(Ag1, &As[0][so1]);
    GLDS16(Bg0, &Bs[0][so0]);
    GLDS16(Bg1, &Bs[0][so1]);
    __syncthreads();

    int cur = 0;
    for (int k0 = 0; k0 < K; k0 += 32) {
        // issue next step's loads into the other buffer (in flight under compute)
        if (k0 + 32 < K) {
            GLDS16(Ag0 + k0 + 32, &As[cur ^ 1][so0]);
            GLDS16(Ag1 + k0 + 32, &As[cur ^ 1][so1]);
            GLDS16(Bg0 + k0 + 32, &Bs[cur ^ 1][so0]);
            GLDS16(Bg1 + k0 + 32, &Bs[cur ^ 1][so1]);
        }
        bf8 af[4], bfr[4];
#pragma unroll
        for (int mt = 0; mt < 4; ++mt) af[mt]  = *(const bf8*)(&As[cur][(wm + mt * 16 + ln) * 32 + quad * 8]);
#pragma unroll
        for (int nt = 0; nt < 4; ++nt) bfr[nt] = *(const bf8*)(&Bs[cur][(wn + nt * 16 + ln) * 32 + quad * 8]);
#pragma unroll
        for (int mt = 0; mt < 4; ++mt)
#pragma unroll
            for (int nt = 0; nt < 4; ++nt)
                acc[mt][nt] = __builtin_amdgcn_mfma_f32_16x16x32_bf16(af[mt], bfr[nt], acc[mt][nt], 0, 0, 0);
        __syncthreads();   // drains in-flight loads (they had the compute to land)
        cur ^= 1;
    }

    // C-layout: m = wm+mt*16+quad*4+r (4 consecutive s), n = wn+nt*16+ln (=d)
    const int sec = n0 >> 10;                      // block-uniform: 0=Q,1=K,2=V
#pragma unroll
    for (int nt = 0; nt < 4; ++nt) {
        const int gn = n0 + wn + nt * 16 + ln;
        const int nn = gn & 1023;
        const int hh = nn >> 6, d = nn & 63;
        const float bias = (sec == 0 ? bq[nn] : (sec == 1 ? bk[nn] : bv[nn]));
        if (sec < 2) {
            bf16_t* dstBase = (sec == 0 ? Qh : Kh);
#pragma unroll
            for (int mt = 0; mt < 4; ++mt) {
#pragma unroll
                for (int r = 0; r < 4; ++r) {
                    const int gm = m0 + wm + mt * 16 + quad * 4 + r;
                    const int b = gm >> 11, s = gm & 2047;
                    dstBase[((size_t)(b * NH + hh) * NS + s) * NHD + d] = (bf16_t)(acc[mt][nt][r] + bias);
                }
            }
        } else {
            // V transposed: [b][h][d][s], 4 consecutive s -> contiguous bf16x4
#pragma unroll
            for (int mt = 0; mt < 4; ++mt) {
                const int gm0 = m0 + wm + mt * 16 + quad * 4;
                const int b = gm0 >> 11, s = gm0 & 2047;
                bf4v pk;
#pragma unroll
                for (int r = 0; r < 4; ++r) pk[r] = (bf16_t)(acc[mt][nt][r] + bias);
                *(bf4v*)(&VTh[((size_t)(b * NH + hh) * NHD + d) * NS + s]) = pk;
            }
        }
    }
}

// ---------------- flash attention ----------------
// v12 = v10 + double-buffered K/V LDS: commit of tile j+1 goes into buf^1
// (safe: buf^1 last read in iter j-1, barrier at end of j-1 intervenes),
// then ONE barrier per iteration (was 2). 36.9 KB LDS. Compute identical to
// v10: swapped QK^T (lane owns q-row ln), fixed m=0 softmax + deferred sums,
// in-register P via permlane32/16 swaps, V^T staged like K, XCD head map,
// LPT, 16-VGPR register prefetch, setprio on MFMA clusters.
__global__ __launch_bounds__(256) void attn_kernel(const bf16_t* __restrict__ Q,
                                                   const bf16_t* __restrict__ K,
                                                   const bf16_t* __restrict__ VT,
                                                   bf16_t* __restrict__ O) {
    __shared__ __align__(16) bf16_t Ks[2][64 * 72];    // [buf][kv][d], padded
    __shared__ __align__(16) bf16_t Vt[2][64 * 72];    // [buf][d][kv], padded
    const int L = blockIdx.x;
    const int mm = L >> 3;
    const int h  = ((mm >> 5) << 3) | (L & 7);         // head 0..63; XCD = L&7
    const int qt = 31 - (mm & 31);                     // LPT: longest first
    const int q0 = qt * 64;
    const int jmax = qt;
    const size_t head_off = (size_t)h * NS * NHD;      // same size for [s,d] and [d,s]
    const int t = threadIdx.x;
    const int wave = t >> 6, lane = t & 63, ln = lane & 15, quad = lane >> 4;

    // per-wave Q strip fragments, 1/sqrt(hd)=0.125 folded in (exact in bf16)
    const bf16_t* Qrow = Q + head_off + (size_t)(q0 + wave * 16 + ln) * NHD;
    bf8 qf0 = *(const bf8*)(Qrow + quad * 8);
    bf8 qf1 = *(const bf8*)(Qrow + 32 + quad * 8);
#pragma unroll
    for (int e = 0; e < 8; ++e) {
        qf0[e] = (bf16_t)((float)qf0[e] * 0.125f);
        qf1[e] = (bf16_t)((float)qf1[e] * 0.125f);
    }

    const bf16_t* Kg  = K  + head_off;                 // [kv][d]
    const bf16_t* VTg = VT + head_off;                 // [d][s]
    const int krow0 = t >> 3, kcol = (t & 7) * 8;      // staging: 8 lanes/row

    // ---- prologue: stage tile 0 into buf 0 ----
    uint4 kr0 = *(const uint4*)(Kg + (size_t)krow0 * NHD + kcol);
    uint4 kr1 = *(const uint4*)(Kg + (size_t)(krow0 + 32) * NHD + kcol);
    uint4 vr0 = *(const uint4*)(VTg + (size_t)krow0 * NS + kcol);
    uint4 vr1 = *(const uint4*)(VTg + (size_t)(krow0 + 32) * NS + kcol);
    *(uint4*)(&Ks[0][krow0 * 72 + kcol])        = kr0;
    *(uint4*)(&Ks[0][(krow0 + 32) * 72 + kcol]) = kr1;
    *(uint4*)(&Vt[0][krow0 * 72 + kcol])        = vr0;
    *(uint4*)(&Vt[0][(krow0 + 32) * 72 + kcol]) = vr1;
    __syncthreads();

    f4 o[4];
    const f4 z = {0.f, 0.f, 0.f, 0.f};
#pragma unroll
    for (int i = 0; i < 4; ++i) o[i] = z;
    float ls = 0.f;                        // per-lane partial sum of row q=ln

#pragma unroll 1
    for (int j = 0; j <= jmax; ++j) {
        const bf16_t* KsB = &Ks[j & 1][0];
        const bf16_t* VtB = &Vt[j & 1][0];
        // ---- prefetch next tile into registers (lands under compute) ----
        if (j < jmax) {
            const size_t nb = (size_t)(j + 1) * 64;
            kr0 = *(const uint4*)(Kg + (nb + krow0) * NHD + kcol);
            kr1 = *(const uint4*)(Kg + (nb + krow0 + 32) * NHD + kcol);
            vr0 = *(const uint4*)(VTg + (size_t)krow0 * NS + nb + kcol);
            vr1 = *(const uint4*)(VTg + (size_t)(krow0 + 32) * NS + nb + kcol);
        }

        // ---- S^T = K @ Q^T (swapped): lane owns q-row ln ----
        // s[nt][r] = S[q = q0+wave*16+ln][kv = j*64 + nt*16 + quad*4 + r]
        f4 s[4];
        __builtin_amdgcn_s_setprio(1);
#pragma unroll
        for (int nt = 0; nt < 4; ++nt) {
            const bf8 kf0 = *(const bf8*)(&KsB[(nt * 16 + ln) * 72 + quad * 8]);
            const bf8 kf1 = *(const bf8*)(&KsB[(nt * 16 + ln) * 72 + 32 + quad * 8]);
            s[nt] = z;
            s[nt] = __builtin_amdgcn_mfma_f32_16x16x32_bf16(kf0, qf0, s[nt], 0, 0, 0);
            s[nt] = __builtin_amdgcn_mfma_f32_16x16x32_bf16(kf1, qf1, s[nt], 0, 0, 0);
        }
        __builtin_amdgcn_s_setprio(0);

        // ---- causal mask (diagonal tile only; block-uniform branch) ----
        if (j == jmax) {
            const int kv0 = j * 64;
            const int rowq = q0 + wave * 16 + ln;
#pragma unroll
            for (int nt = 0; nt < 4; ++nt) {
#pragma unroll
                for (int r = 0; r < 4; ++r)
                    if (kv0 + nt * 16 + quad * 4 + r > rowq) s[nt][r] = -1e30f;
            }
        }

        // ---- p = exp(s) (m fixed at 0), per-lane scalar partial sum ----
#pragma unroll
        for (int nt = 0; nt < 4; ++nt)
#pragma unroll
            for (int r = 0; r < 4; ++r) {
                const float p = __expf(s[nt][r]);
                s[nt][r] = p;
                ls += p;
            }

        // ---- P -> PV A-fragments fully in registers (no LDS) ----
        unsigned int w[4][2];
#pragma unroll
        for (int nt = 0; nt < 4; ++nt)
#pragma unroll
            for (int rr = 0; rr < 2; ++rr) {
                union { bf16_t hx[2]; unsigned int u; } u;
                u.hx[0] = (bf16_t)s[nt][2 * rr];
                u.hx[1] = (bf16_t)s[nt][2 * rr + 1];
                w[nt][rr] = u.u;
            }
        union Frag { unsigned int d[4]; bf8 v; } f0, f1;
        {
            unsigned int a, b;
            a = w[0][0]; b = w[1][0];
            asm volatile("v_permlane32_swap_b32 %0, %1" : "+v"(a), "+v"(b));
            asm volatile("v_permlane16_swap_b32 %0, %1" : "+v"(a), "+v"(b));
            f0.d[0] = a; f0.d[2] = b;
            a = w[0][1]; b = w[1][1];
            asm volatile("v_permlane32_swap_b32 %0, %1" : "+v"(a), "+v"(b));
            asm volatile("v_permlane16_swap_b32 %0, %1" : "+v"(a), "+v"(b));
            f0.d[1] = a; f0.d[3] = b;
            a = w[2][0]; b = w[3][0];
            asm volatile("v_permlane32_swap_b32 %0, %1" : "+v"(a), "+v"(b));
            asm volatile("v_permlane16_swap_b32 %0, %1" : "+v"(a), "+v"(b));
            f1.d[0] = a; f1.d[2] = b;
            a = w[2][1]; b = w[3][1];
            asm volatile("v_permlane32_swap_b32 %0, %1" : "+v"(a), "+v"(b));
            asm volatile("v_permlane16_swap_b32 %0, %1" : "+v"(a), "+v"(b));
            f1.d[1] = a; f1.d[3] = b;
        }
        const bf8 p0 = f0.v;
        const bf8 p1 = f1.v;

        // ---- O += P @ V ----
        __builtin_amdgcn_s_setprio(1);
#pragma unroll
        for (int dt = 0; dt < 4; ++dt) {
            const bf8 v0 = *(const bf8*)(&VtB[(dt * 16 + ln) * 72 + quad * 8]);
            const bf8 v1 = *(const bf8*)(&VtB[(dt * 16 + ln) * 72 + 32 + quad * 8]);
            o[dt] = __builtin_amdgcn_mfma_f32_16x16x32_bf16(p0, v0, o[dt], 0, 0, 0);
            o[dt] = __builtin_amdgcn_mfma_f32_16x16x32_bf16(p1, v1, o[dt], 0, 0, 0);
        }
        __builtin_amdgcn_s_setprio(0);

        // ---- commit prefetched tile into the OTHER buffer (no pre-barrier:
        //      buf^1 was last read in iter j-1; that iter's end barrier
        //      guarantees no wave still reads it) ----
        if (j < jmax) {
            bf16_t* KsN = &Ks[(j + 1) & 1][0];
            bf16_t* VtN = &Vt[(j + 1) & 1][0];
            *(uint4*)(&KsN[krow0 * 72 + kcol])        = kr0;
            *(uint4*)(&KsN[(krow0 + 32) * 72 + kcol]) = kr1;
            *(uint4*)(&VtN[krow0 * 72 + kcol])        = vr0;
            *(uint4*)(&VtN[(krow0 + 32) * 72 + kcol]) = vr1;
        }
        __syncthreads();   // single barrier per iteration
    }

    // ---- epilogue: complete row sums (quads hold disjoint kv subsets) ----
    ls += __shfl_xor(ls, 16);
    ls += __shfl_xor(ls, 32);   // now every lane has the full sum of row q=ln

    const int b = h >> 4, hh = h & 15;
#pragma unroll
    for (int r = 0; r < 4; ++r) {
        // output row of this lane is quad*4+r; its sum lives on lane quad*4+r
        const float inv = 1.f / __shfl(ls, quad * 4 + r);
        const int gs = q0 + wave * 16 + quad * 4 + r;
#pragma unroll
        for (int dt = 0; dt < 4; ++dt)
            O[((size_t)(b * NS + gs)) * ND + hh * NHD + dt * 16 + ln] = (bf16_t)(o[dt][r] * inv);
    }
}

// ---------------- output projection GEMM ----------------
// v12: depth-1 2-phase (same as qkv); swapped-operand epilogue (float4 stores).
__global__ __launch_bounds__(256) void gemm_proj(const bf16_t* __restrict__ A,
                                                 const bf16_t* __restrict__ Bw,
                                                 const float* __restrict__ bo,
                                                 const float* __restrict__ comp,
                                                 float* __restrict__ out) {
    __shared__ __align__(16) bf16_t As[2][128 * 32];
    __shared__ __align__(16) bf16_t Bs[2][128 * 32];
    const int t = threadIdx.x;
    const int wave = t >> 6, lane = t & 63, ln = lane & 15, quad = lane >> 4;
    const int wm = (wave >> 1) * 64, wn = (wave & 1) * 64;
    const int nwg = gridDim.x * gridDim.y;
    int flat = blockIdx.y * gridDim.x + blockIdx.x;
    flat = (flat & 7) * (nwg >> 3) + (flat >> 3);
    const int m0 = (flat / gridDim.x) * 128, n0 = (flat % gridDim.x) * 128;
    const int K = 1024;

    f4 acc[4][4];
    const f4 z = {0.f, 0.f, 0.f, 0.f};
#pragma unroll
    for (int i = 0; i < 4; ++i)
#pragma unroll
        for (int j = 0; j < 4; ++j) acc[i][j] = z;

    const int srow = wave * 16 + (lane >> 2);
    const int scol = (lane & 3) * 8;
    const bf16_t* Ag0 = A  + (size_t)(m0 + srow) * K + scol;
    const bf16_t* Ag1 = A  + (size_t)(m0 + srow + 64) * K + scol;
    const bf16_t* Bg0 = Bw + (size_t)(n0 + srow) * K + scol;
    const bf16_t* Bg1 = Bw + (size_t)(n0 + srow + 64) * K + scol;
    const int so0 = srow * 32 + scol, so1 = (srow + 64) * 32 + scol;

    GLDS16(Ag0, &As[0][so0]);
    GLDS16(Ag1, &As[0][so1]);
    GLDS16(Bg0, &Bs[0][so0]);
    GLDS16(Bg1, &Bs[0][so1]);
    __syncthreads();

    int cur = 0;
    for (int k0 = 0; k0 < K; k0 += 32) {
        if (k0 + 32 < K) {
            GLDS16(Ag0 + k0 + 32, &As[cur ^ 1][so0]);
            GLDS16(Ag1 + k0 + 32, &As[cur ^ 1][so1]);
            GLDS16(Bg0 + k0 + 32, &Bs[cur ^ 1][so0]);
            GLDS16(Bg1 + k0 + 32, &Bs[cur ^ 1][so1]);
        }
        bf8 af[4], bfr[4];
#pragma unroll
        for (int mt = 0; mt < 4; ++mt) af[mt]  = *(const bf8*)(&As[cur][(wm + mt * 16 + ln) * 32 + quad * 8]);
#pragma unroll
        for (int nt = 0; nt < 4; ++nt) bfr[nt] = *(const bf8*)(&Bs[cur][(wn + nt * 16 + ln) * 32 + quad * 8]);
#pragma unroll
        for (int mt = 0; mt < 4; ++mt)
#pragma unroll
            for (int nt = 0; nt < 4; ++nt)
                acc[mt][nt] = __builtin_amdgcn_mfma_f32_16x16x32_bf16(bfr[nt], af[mt], acc[mt][nt], 0, 0, 0);
        __syncthreads();
        cur ^= 1;
    }

    // swapped C-layout: m = wm+mt*16+ln, n = wn+nt*16+quad*4+r
#pragma unroll
    for (int nt = 0; nt < 4; ++nt) {
        const int gn = n0 + wn + nt * 16 + quad * 4;
        const float4 b4 = *(const float4*)(bo + gn);
        const float4 c4 = *(const float4*)(comp + gn);
#pragma unroll
        for (int mt = 0; mt < 4; ++mt) {
            const int gm = m0 + wm + mt * 16 + ln;
            float4 v;
            v.x = acc[mt][nt][0] + b4.x + c4.x;
            v.y = acc[mt][nt][1] + b4.y + c4.y;
            v.z = acc[mt][nt][2] + b4.z + c4.z;
            v.w = acc[mt][nt][3] + b4.w + c4.w;
            *(float4*)(&out[(size_t)gm * ND + gn]) = v;
        }
    }
}

extern "C" void kernel_launch(void* const* d_in, const int* in_sizes, int n_in,
                              void* d_out, int out_size, void* d_ws, size_t ws_size,
                              hipStream_t stream) {
    const float* x    = (const float*)d_in[0];
    const float* Wq   = (const float*)d_in[1];
    const float* bq   = (const float*)d_in[2];
    const float* Wk   = (const float*)d_in[3];
    const float* bk   = (const float*)d_in[4];
    const float* Wv   = (const float*)d_in[5];
    const float* bv   = (const float*)d_in[6];
    const float* Wo   = (const float*)d_in[7];
    const float* bo   = (const float*)d_in[8];
    const float* comp = (const float*)d_in[9];
    float* out = (float*)d_out;

    char* w = (char*)d_ws;
    bf16_t* Xb   = (bf16_t*)(w);                         // 8192x1024
    bf16_t* Wqkv = (bf16_t*)(w + 16777216);              // 3072x1024
    bf16_t* Wob  = (bf16_t*)(w + 23068672);              // 1024x1024
    bf16_t* Qh   = (bf16_t*)(w + 25165824);              // [B,H,S,hd]
    bf16_t* Kh   = (bf16_t*)(w + 41943040);              // [B,H,S,hd]
    bf16_t* VTh  = (bf16_t*)(w + 58720256);              // [B,H,hd,S]  (transposed!)
    bf16_t* AOb  = (bf16_t*)(w + 75497472);              // 8192x1024

    cvt_all<<<12288, 256, 0, stream>>>(x, Wq, Wk, Wv, Wo, Xb, Wqkv, Wob);
    gemm_qkv<<<dim3(3072 / 128, NM / 128), 256, 0, stream>>>(Xb, Wqkv, bq, bk, bv, Qh, Kh, VTh);
    attn_kernel<<<2048, 256, 0, stream>>>(Qh, Kh, VTh, AOb);
    gemm_proj<<<dim3(1024 / 128, NM / 128), 256, 0, stream>>>(AOb, Wob, bo, comp, out);
}